// Round 7
// baseline (446.768 us; speedup 1.0000x reference)
//
#include <hip/hip_runtime.h>
#include <hip/hip_bf16.h>
#include <hip/hip_cooperative_groups.h>

namespace cg = cooperative_groups;

// Problem constants
#define HEIGHT 480
#define WIDTH  640
#define IN_CH  6
#define CIN    8      // p, 1-p, 6 features
#define COUT   32
#define BATCH  8
#define NPTS   16384
#define NPTOT  (BATCH * NPTS)          // 131072 = 2^17
// Padded grid: rows 0..482 (point rows 1..481), cols 0..642 (point cols 1..641)
#define GH 483
#define GW 643
#define NCELLS ((size_t)BATCH * GH * GW)   // 2,484,552 cells (divisible by 4)

// grid layout: [b][gy][gx][cin], cin contiguous (32B per cell, 32B-aligned)
__device__ __forceinline__ size_t cell_idx(int b, int gy, int gx) {
    return ((size_t)b * GH + gy) * GW + gx;
}

__device__ __forceinline__ void point_cell(const float4 q, int point,
                                           int& b, int& gy, int& gx) {
    gy = (int)rintf(q.z * (float)HEIGHT) + 1;   // padded coord
    gx = (int)rintf(q.y * (float)WIDTH) + 1;
    b  = point >> 14;                           // NPTS = 16384
}

__device__ __forceinline__ void conv_point(int idx,
                                           const float4* __restrict__ xytp,
                                           const float*  __restrict__ grid,
                                           const unsigned int* __restrict__ cnt,
                                           const float*  __restrict__ W,
                                           const float*  __restrict__ bias,
                                           float* __restrict__ out) {
    float4 q = xytp[idx];
    int b, gy, gx;
    point_cell(q, idx, b, gy, gx);              // padded top-left is (gy-1+0 .. ), see below
    // window top-left in padded coords = (gy-1, gx-1); cell_idx(b, gy-1, gx-1)
    size_t base_ci = cell_idx(b, gy - 1, gx - 1);

    float acc[COUT];
#pragma unroll
    for (int c = 0; c < COUT; ++c) acc[c] = bias[c];

#pragma unroll
    for (int ky = 0; ky < 3; ++ky) {
#pragma unroll
        for (int kx = 0; kx < 3; ++kx) {
            size_t ci = base_ci + (size_t)(ky * GW + kx);
            if (cnt[ci] != 0u) {
                const float* cell = grid + (ci << 3);
                float4 g0 = *(const float4*)(cell);
                float4 g1 = *(const float4*)(cell + 4);
                float gv[CIN] = {g0.x, g0.y, g0.z, g0.w, g1.x, g1.y, g1.z, g1.w};
                const float* wp = W + (ky * 3 + kx) * CIN * COUT;
#pragma unroll
                for (int ci2 = 0; ci2 < CIN; ++ci2) {
#pragma unroll
                    for (int c = 0; c < COUT; ++c) {
                        acc[c] = fmaf(gv[ci2], wp[ci2 * COUT + c], acc[c]);
                    }
                }
            }
        }
    }

    float* o = out + (size_t)idx * COUT;
#pragma unroll
    for (int c = 0; c < COUT; c += 4) {
        *(float4*)(o + c) = make_float4(acc[c], acc[c + 1], acc[c + 2], acc[c + 3]);
    }
}

__device__ __forceinline__ void write_point(int point,
                                            const float4* __restrict__ xytp,
                                            const float*  __restrict__ feats,
                                            const unsigned int* __restrict__ cnt,
                                            float* __restrict__ grid) {
    float4 q = xytp[point];
    int b, gy, gx;
    point_cell(q, point, b, gy, gx);
    size_t ci = cell_idx(b, gy, gx);

    const float* f = feats + (size_t)point * IN_CH;
    float v0 = q.w, v1 = 1.0f - q.w;
    float f0 = f[0], f1 = f[1], f2 = f[2], f3 = f[3], f4 = f[4], f5 = f[5];

    float* cell = grid + (ci << 3);
    if (cnt[ci] == 1u) {
        *(float4*)(cell)     = make_float4(v0, v1, f0, f1);
        *(float4*)(cell + 4) = make_float4(f2, f3, f4, f5);
    } else {
        unsafeAtomicAdd(cell + 0, v0);
        unsafeAtomicAdd(cell + 1, v1);
        unsafeAtomicAdd(cell + 2, f0);
        unsafeAtomicAdd(cell + 3, f1);
        unsafeAtomicAdd(cell + 4, f2);
        unsafeAtomicAdd(cell + 5, f3);
        unsafeAtomicAdd(cell + 6, f4);
        unsafeAtomicAdd(cell + 7, f5);
    }
}

// ---------- Fused cooperative kernel: all 5 phases, grid.sync() between ----------
__global__ void __launch_bounds__(256, 4)
fused_kernel(const float4* __restrict__ xytp,
             const float*  __restrict__ feats,
             const float*  __restrict__ W,
             const float*  __restrict__ bias,
             unsigned int* __restrict__ cnt,
             float* __restrict__ grid,
             float* __restrict__ out) {
    cg::grid_group g = cg::this_grid();
    const unsigned tid = blockIdx.x * blockDim.x + threadIdx.x;
    const unsigned nth = gridDim.x * blockDim.x;

    // Phase 0: zero counters (uint4 sweep)
    uint4* cnt4 = (uint4*)cnt;
    for (size_t i = tid; i < NCELLS / 4; i += nth)
        cnt4[i] = make_uint4(0u, 0u, 0u, 0u);
    g.sync();

    // Phase 1: count (1 u32 atomic per point)
    for (unsigned p = tid; p < NPTOT; p += nth) {
        float4 q = xytp[p];
        int b, gy, gx;
        point_cell(q, (int)p, b, gy, gx);
        atomicAdd(&cnt[cell_idx(b, gy, gx)], 1u);
    }
    g.sync();

    // Phase 2: zero only multi-point cells (cnt>=2)
    const float4 z = make_float4(0.f, 0.f, 0.f, 0.f);
    for (size_t i4 = tid; i4 < NCELLS / 4; i4 += nth) {
        uint4 c4 = cnt4[i4];
        size_t i = i4 << 2;
#pragma unroll
        for (int k = 0; k < 4; ++k) {
            unsigned c = (k == 0) ? c4.x : (k == 1) ? c4.y : (k == 2) ? c4.z : c4.w;
            if (c >= 2u) {
                float* cell = grid + ((i + k) << 3);
                *(float4*)(cell)     = z;
                *(float4*)(cell + 4) = z;
            }
        }
    }
    g.sync();

    // Phase 3: write features (store if cnt==1, atomics if >=2)
    for (unsigned p = tid; p < NPTOT; p += nth)
        write_point((int)p, xytp, feats, cnt, grid);
    g.sync();

    // Phase 4: conv + gather at point cells
    for (unsigned p = tid; p < NPTOT; p += nth)
        conv_point((int)p, xytp, grid, cnt, W, bias, out);
}

// ---------- Fallback multi-kernel path (if cooperative launch unavailable) ----------
__global__ void zero_cnt_kernel(uint4* __restrict__ cnt4) {
    size_t i = (size_t)blockIdx.x * blockDim.x + threadIdx.x;
    if (i < NCELLS / 4) cnt4[i] = make_uint4(0u, 0u, 0u, 0u);
}

__global__ void count_kernel(const float4* __restrict__ xytp,
                             unsigned int* __restrict__ cnt) {
    int point = blockIdx.x * blockDim.x + threadIdx.x;
    if (point >= NPTOT) return;
    float4 q = xytp[point];
    int b, gy, gx;
    point_cell(q, point, b, gy, gx);
    atomicAdd(&cnt[cell_idx(b, gy, gx)], 1u);
}

__global__ void prep_kernel(const unsigned int* __restrict__ cnt,
                            float* __restrict__ grid) {
    size_t i = (size_t)(blockIdx.x * blockDim.x + threadIdx.x) * 4;
    if (i >= NCELLS) return;
    uint4 c4 = *(const uint4*)(cnt + i);
    const float4 z = make_float4(0.f, 0.f, 0.f, 0.f);
#pragma unroll
    for (int k = 0; k < 4; ++k) {
        unsigned int c = (k == 0) ? c4.x : (k == 1) ? c4.y : (k == 2) ? c4.z : c4.w;
        if (c >= 2u) {
            float* cell = grid + ((i + k) << 3);
            *(float4*)(cell)     = z;
            *(float4*)(cell + 4) = z;
        }
    }
}

__global__ void write_kernel(const float4* __restrict__ xytp,
                             const float*  __restrict__ feats,
                             const unsigned int* __restrict__ cnt,
                             float* __restrict__ grid) {
    int point = blockIdx.x * blockDim.x + threadIdx.x;
    if (point >= NPTOT) return;
    write_point(point, xytp, feats, cnt, grid);
}

__global__ void conv_gather_kernel(const float4* __restrict__ xytp,
                                   const float*  __restrict__ grid,
                                   const unsigned int* __restrict__ cnt,
                                   const float*  __restrict__ W,
                                   const float*  __restrict__ bias,
                                   float* __restrict__ out) {
    int idx = blockIdx.x * blockDim.x + threadIdx.x;
    if (idx >= NPTOT) return;
    conv_point(idx, xytp, grid, cnt, W, bias, out);
}

extern "C" void kernel_launch(void* const* d_in, const int* in_sizes, int n_in,
                              void* d_out, int out_size, void* d_ws, size_t ws_size,
                              hipStream_t stream) {
    const float4* xytp  = (const float4*)d_in[0];   // (8,16384,4)
    const float*  feats = (const float*)d_in[1];    // (8,16384,6)
    const float*  W     = (const float*)d_in[2];    // (3,3,8,32)
    const float*  bias  = (const float*)d_in[3];    // (32,)
    float* out = (float*)d_out;                     // (8,16384,32)

    float* grid = (float*)d_ws;
    const size_t grid_bytes = NCELLS * CIN * sizeof(float);      // ~79.5 MB
    unsigned int* cnt = (unsigned int*)((char*)d_ws + grid_bytes);
    (void)ws_size;

    // One cooperative kernel: 1024 blocks x 256 thr, __launch_bounds__(256,4)
    // caps VGPR at 128 -> 4 blocks/CU co-resident on 256 CUs.
    void* args[] = {(void*)&xytp, (void*)&feats, (void*)&W, (void*)&bias,
                    (void*)&cnt, (void*)&grid, (void*)&out};
    hipError_t err = hipLaunchCooperativeKernel((const void*)fused_kernel,
                                                dim3(1024), dim3(256),
                                                args, 0, stream);
    if (err == hipSuccess) return;

    // Fallback: 5-dispatch pipeline (round-6 structure)
    const int blk = 256;
    const int nblk_pts = (NPTOT + blk - 1) / blk;
    const size_t n_fill = NCELLS / 4;
    zero_cnt_kernel<<<(int)((n_fill + blk - 1) / blk), blk, 0, stream>>>((uint4*)cnt);
    count_kernel<<<nblk_pts, blk, 0, stream>>>(xytp, cnt);
    prep_kernel<<<(int)((n_fill + blk - 1) / blk), blk, 0, stream>>>(cnt, grid);
    write_kernel<<<nblk_pts, blk, 0, stream>>>(xytp, feats, cnt, grid);
    conv_gather_kernel<<<nblk_pts, blk, 0, stream>>>(xytp, grid, cnt, W, bias, out);
}

// Round 8
// 44.968 us; speedup vs baseline: 9.9352x; 9.9352x over previous
//
#include <hip/hip_runtime.h>
#include <hip/hip_bf16.h>

// Problem constants
#define HEIGHT 480
#define WIDTH  640
#define IN_CH  6
#define CIN    8      // p, 1-p, 6 features
#define COUT   32
#define BATCH  8
#define NPTS   16384
#define NPTOT  (BATCH * NPTS)          // 131072 = 2^17
// Padded grid: rows 0..482 (point rows 1..481), cols 0..642 (point cols 1..641)
#define GH 483
#define GW 643
#define NCELLS ((size_t)BATCH * GH * GW)   // 2,484,552 cells
#define NWORDS 77644                       // ceil(NCELLS/32)=77643, +1 guard word

// grid layout: [b][gy][gx][cin], cin contiguous (32B per cell, 32B-aligned)
__device__ __forceinline__ size_t cell_idx(int b, int gy, int gx) {
    return ((size_t)b * GH + gy) * GW + gx;
}

__device__ __forceinline__ void point_cell(const float4 q, int point,
                                           int& b, int& gy, int& gx) {
    gy = (int)rintf(q.z * (float)HEIGHT) + 1;   // padded coord
    gx = (int)rintf(q.y * (float)WIDTH) + 1;
    b  = point >> 14;                           // NPTS = 16384
}

// Phase 0: zero both bitmask arrays (2*NWORDS u32 = 621 KB, contiguous).
__global__ void zero_masks_kernel(uint4* __restrict__ m4, int n4) {
    int i = blockIdx.x * blockDim.x + threadIdx.x;
    if (i < n4) m4[i] = make_uint4(0u, 0u, 0u, 0u);
}

// Phase 1: per point, set occupancy bit; if already set, set multi bit.
__global__ void count_kernel(const float4* __restrict__ xytp,
                             unsigned int* __restrict__ occ,
                             unsigned int* __restrict__ multi) {
    int point = blockIdx.x * blockDim.x + threadIdx.x;
    if (point >= NPTOT) return;
    float4 q = xytp[point];
    int b, gy, gx;
    point_cell(q, point, b, gy, gx);
    size_t ci = cell_idx(b, gy, gx);
    unsigned int word = (unsigned int)(ci >> 5);
    unsigned int bit  = 1u << (ci & 31);
    unsigned int old = atomicOr(&occ[word], bit);
    if (old & bit) atomicOr(&multi[word], bit);    // rare (~3%)
}

// Phase 2: zero only grid cells that will be accumulated into (multi bits).
// 310KB coalesced sweep; ~4K scattered 32B zero-stores.
__global__ void prep_kernel(const unsigned int* __restrict__ multi,
                            float* __restrict__ grid) {
    int w = blockIdx.x * blockDim.x + threadIdx.x;
    if (w >= NWORDS) return;
    unsigned int m = multi[w];
    const float4 z = make_float4(0.f, 0.f, 0.f, 0.f);
    while (m) {
        int bpos = __ffs(m) - 1;
        m &= m - 1;
        size_t ci = ((size_t)w << 5) + bpos;
        float* cell = grid + (ci << 3);
        *(float4*)(cell)     = z;
        *(float4*)(cell + 4) = z;
    }
}

// Phase 3: multi bit clear (~97%) -> plain 32B store; else 8 f32 HW atomics.
__global__ void write_kernel(const float4* __restrict__ xytp,
                             const float*  __restrict__ feats,
                             const unsigned int* __restrict__ multi,
                             float* __restrict__ grid) {
    int point = blockIdx.x * blockDim.x + threadIdx.x;
    if (point >= NPTOT) return;
    float4 q = xytp[point];
    int b, gy, gx;
    point_cell(q, point, b, gy, gx);
    size_t ci = cell_idx(b, gy, gx);

    const float* f = feats + (size_t)point * IN_CH;
    float v0 = q.w, v1 = 1.0f - q.w;
    float f0 = f[0], f1 = f[1], f2 = f[2], f3 = f[3], f4 = f[4], f5 = f[5];

    unsigned int word = (unsigned int)(ci >> 5);
    unsigned int bit  = 1u << (ci & 31);

    float* cell = grid + (ci << 3);
    if (!(multi[word] & bit)) {
        *(float4*)(cell)     = make_float4(v0, v1, f0, f1);
        *(float4*)(cell + 4) = make_float4(f2, f3, f4, f5);
    } else {
        unsafeAtomicAdd(cell + 0, v0);
        unsafeAtomicAdd(cell + 1, v1);
        unsafeAtomicAdd(cell + 2, f0);
        unsafeAtomicAdd(cell + 3, f1);
        unsafeAtomicAdd(cell + 4, f2);
        unsafeAtomicAdd(cell + 5, f3);
        unsafeAtomicAdd(cell + 6, f4);
        unsafeAtomicAdd(cell + 7, f5);
    }
}

// Phase 4: one thread per point, all 32 output channels.
// Occupancy test via the 310KB occ bitmask (L1/L2-resident) - empty cells
// hold garbage and must be skipped; also cuts grid gathers ~6x.
__global__ void conv_gather_kernel(const float4* __restrict__ xytp,
                                   const float*  __restrict__ grid,
                                   const unsigned int* __restrict__ occ,
                                   const float*  __restrict__ W,     // [3][3][8][32]
                                   const float*  __restrict__ bias,  // [32]
                                   float* __restrict__ out) {
    int idx = blockIdx.x * blockDim.x + threadIdx.x;
    if (idx >= NPTOT) return;
    float4 q = xytp[idx];
    int b, gy, gx;
    point_cell(q, idx, b, gy, gx);              // padded center
    size_t base_ci = cell_idx(b, gy - 1, gx - 1);   // padded window top-left

    float acc[COUT];
#pragma unroll
    for (int c = 0; c < COUT; ++c) acc[c] = bias[c];

#pragma unroll
    for (int ky = 0; ky < 3; ++ky) {
        size_t ci_row = base_ci + (size_t)ky * GW;
        size_t word = ci_row >> 5;
        int sh = (int)(ci_row & 31);
        unsigned int w0 = occ[word];
        unsigned int w1 = occ[word + 1];            // guard word padded
        unsigned int bits = (unsigned int)(((((unsigned long long)w1) << 32) | w0) >> sh) & 7u;
#pragma unroll
        for (int kx = 0; kx < 3; ++kx) {
            if (bits & (1u << kx)) {
                size_t ci = ci_row + kx;
                const float* cell = grid + (ci << 3);
                float4 g0 = *(const float4*)(cell);
                float4 g1 = *(const float4*)(cell + 4);
                float gv[CIN] = {g0.x, g0.y, g0.z, g0.w, g1.x, g1.y, g1.z, g1.w};
                const float* wp = W + (ky * 3 + kx) * CIN * COUT;
#pragma unroll
                for (int ci2 = 0; ci2 < CIN; ++ci2) {
#pragma unroll
                    for (int c = 0; c < COUT; ++c) {
                        acc[c] = fmaf(gv[ci2], wp[ci2 * COUT + c], acc[c]);
                    }
                }
            }
        }
    }

    float* o = out + (size_t)idx * COUT;
#pragma unroll
    for (int c = 0; c < COUT; c += 4) {
        *(float4*)(o + c) = make_float4(acc[c], acc[c + 1], acc[c + 2], acc[c + 3]);
    }
}

extern "C" void kernel_launch(void* const* d_in, const int* in_sizes, int n_in,
                              void* d_out, int out_size, void* d_ws, size_t ws_size,
                              hipStream_t stream) {
    const float4* xytp  = (const float4*)d_in[0];   // (8,16384,4)
    const float*  feats = (const float*)d_in[1];    // (8,16384,6)
    const float*  W     = (const float*)d_in[2];    // (3,3,8,32)
    const float*  bias  = (const float*)d_in[3];    // (32,)
    float* out = (float*)d_out;                     // (8,16384,32)

    float* grid = (float*)d_ws;                     // 79.5 MB
    const size_t grid_bytes = NCELLS * CIN * sizeof(float);
    unsigned int* occ   = (unsigned int*)((char*)d_ws + grid_bytes);
    unsigned int* multi = occ + NWORDS;
    (void)ws_size;

    const int blk = 256;
    const int nblk_pts = (NPTOT + blk - 1) / blk;   // 512

    // Phase 0: zero both masks (contiguous 2*NWORDS u32; NWORDS % 4 == 0)
    const int n4 = (2 * NWORDS) / 4;                // 38,822 uint4
    zero_masks_kernel<<<(n4 + blk - 1) / blk, blk, 0, stream>>>((uint4*)occ, n4);

    count_kernel<<<nblk_pts, blk, 0, stream>>>(xytp, occ, multi);

    prep_kernel<<<(NWORDS + blk - 1) / blk, blk, 0, stream>>>(multi, grid);

    write_kernel<<<nblk_pts, blk, 0, stream>>>(xytp, feats, multi, grid);

    conv_gather_kernel<<<nblk_pts, blk, 0, stream>>>(xytp, grid, occ, W, bias, out);
}